// Round 2
// 436.190 us; speedup vs baseline: 1.2279x; 1.2279x over previous
//
#include <hip/hip_runtime.h>
#include <math.h>

#define TOKENS 16384
#define EMBD   4096
#define NEXP   64
#define TOPK   8
#define KSPLIT 8
#define KSLICE (EMBD / KSPLIT)   /* 512 */
#define CHUNK  16
#define EHALF  32                /* experts per wave (64 split across wave pairs) */

// ---------------------------------------------------------------------------
// Kernel 1: transpose W[64][4096] -> Wt[4096][64] so that for a fixed k the
// expert weights are contiguous (enables s_load_dwordx16 scalar loads).
// ---------------------------------------------------------------------------
__global__ void transpose_w(const float* __restrict__ W, float* __restrict__ Wt) {
    int idx = blockIdx.x * blockDim.x + threadIdx.x;  // idx = e*4096 + k
    int e = idx >> 12;
    int k = idx & 4095;
    Wt[k * NEXP + e] = W[idx];
}

// ---------------------------------------------------------------------------
// Kernel 2: partial GEMM. lane = token; each wave handles HALF the experts
// (32) so the f64 chunk accumulator fits in VGPRs (32*2 + 32 + 16 ~= 128,
// no spill -- the old 64-expert version needed 128 VGPRs for accd alone and
// showed 2-3x write inflation from spill traffic). Wave pairs (wave 0/1 and
// 2/3) process the same 64 tokens, so their duplicate x reads hit L1.
// Grid doubles to 1024 blocks -> 12 waves/CU instead of 8.
// Numerics: identical fma order / chunk boundaries / f64 chunk accumulation
// as the previous passing version -> logits are BIT-IDENTICAL.
// Grid: (TOKENS/128) x KSPLIT = 1024 blocks of 256.
// ---------------------------------------------------------------------------
__global__ __launch_bounds__(256, 3) void gemm_partial(
    const float* __restrict__ x, const float* __restrict__ Wt,
    float* __restrict__ part) {
    const int lane = threadIdx.x & 63;
    const int wave = threadIdx.x >> 6;
    const int tgrp = wave >> 1;                     // token group within block
    // expert half: wave-uniform in fact, but threadIdx-derived -> hoist to
    // SGPR so the W loads stay scalar (s_load) instead of per-lane vector.
    const int half = __builtin_amdgcn_readfirstlane(wave & 1);
    const int tok  = blockIdx.x * 128 + tgrp * 64 + lane;
    const int ks   = blockIdx.y;
    const int kbase = ks * KSLICE;

    const float* xrow  = x + (size_t)tok * EMBD + kbase;
    const float* wbase = Wt + (size_t)kbase * NEXP + half * EHALF;  // wave-uniform

    double accd[EHALF];
#pragma unroll
    for (int e = 0; e < EHALF; ++e) accd[e] = 0.0;

    for (int kc = 0; kc < KSLICE; kc += CHUNK) {
        const float4* xp = (const float4*)(xrow + kc);
        float4 a = xp[0], b = xp[1], c = xp[2], d4 = xp[3];
        float xv[CHUNK] = {a.x, a.y, a.z, a.w,  b.x, b.y, b.z, b.w,
                           c.x, c.y, c.z, c.w,  d4.x, d4.y, d4.z, d4.w};

        float accf[EHALF];
#pragma unroll
        for (int e = 0; e < EHALF; ++e) accf[e] = 0.0f;

#pragma unroll
        for (int j = 0; j < CHUNK; ++j) {
            const float xj = xv[j];
            const float* wrow = wbase + (size_t)(kc + j) * NEXP;  // wave-uniform
#pragma unroll
            for (int e = 0; e < EHALF; ++e)
                accf[e] = fmaf(wrow[e], xj, accf[e]);
        }

#pragma unroll
        for (int e = 0; e < EHALF; ++e) accd[e] += (double)accf[e];
    }

    float4* dst = (float4*)(part + ((size_t)ks * TOKENS + tok) * NEXP
                            + (size_t)half * EHALF);
#pragma unroll
    for (int v = 0; v < EHALF / 4; ++v)
        dst[v] = make_float4((float)accd[4 * v],     (float)accd[4 * v + 1],
                             (float)accd[4 * v + 2], (float)accd[4 * v + 3]);
}

// ---------------------------------------------------------------------------
// Kernel 3: reduce K-split partials (fixed order f64 -> logits bit-identical
// to previous version), then RANK-BASED top-8: stage the 64 logits in LDS,
// each lane counts how many logits beat its own (ties -> lower index wins,
// exactly jax.lax.top_k's stable order). Replaces the old 96-deep serial
// __shfl_xor argmax chain with ~300 straight-line ops.
// One wave per token, 4 tokens per block.
// ---------------------------------------------------------------------------
__global__ __launch_bounds__(256) void topk_softmax(
    const float* __restrict__ part, float* __restrict__ probs,
    float* __restrict__ idxout) {
    __shared__ float lval[4][NEXP];
    __shared__ float lidx[4][TOPK];

    const int lane = threadIdx.x & 63;   // = expert
    const int wave = threadIdx.x >> 6;
    const int tok  = blockIdx.x * 4 + wave;

    double d = 0.0;
#pragma unroll
    for (int s = 0; s < KSPLIT; ++s)
        d += (double)part[((size_t)s * TOKENS + tok) * NEXP + lane];
    const float logit = (float)d;

    lval[wave][lane] = logit;
    __syncthreads();

    // rank = #{j : v_j > v_lane} + #{j : v_j == v_lane && j < lane}
    // (selection set + order identical to the old iterative argmax)
    const float4* lv4 = (const float4*)lval[wave];  // broadcast reads
    int rank = 0;
    float m = -INFINITY;
#pragma unroll
    for (int q4 = 0; q4 < NEXP / 4; ++q4) {
        float4 v = lv4[q4];
        const int qb = q4 * 4;
        rank += (v.x > logit || (v.x == logit && qb + 0 < lane)) ? 1 : 0;
        rank += (v.y > logit || (v.y == logit && qb + 1 < lane)) ? 1 : 0;
        rank += (v.z > logit || (v.z == logit && qb + 2 < lane)) ? 1 : 0;
        rank += (v.w > logit || (v.w == logit && qb + 3 < lane)) ? 1 : 0;
        m = fmaxf(fmaxf(m, v.x), fmaxf(v.y, fmaxf(v.z, v.w)));
    }

    const bool sel = rank < TOPK;
    const float t  = sel ? expf(logit - m) : 0.0f;

    // denominator: wave-wide sum of selected exps (order differs from old
    // version by ~1 ulp only; selection itself is on bit-identical logits)
    float denom = t;
#pragma unroll
    for (int off = 32; off > 0; off >>= 1)
        denom += __shfl_xor(denom, off);

    if (sel) lidx[wave][rank] = (float)lane;   // scatter index by rank
    __syncthreads();

    probs[(size_t)tok * NEXP + lane] = sel ? (t / denom) : 0.0f;
    if (lane < TOPK) idxout[(size_t)tok * TOPK + lane] = lidx[wave][lane];
}

// ---------------------------------------------------------------------------
extern "C" void kernel_launch(void* const* d_in, const int* in_sizes, int n_in,
                              void* d_out, int out_size, void* d_ws, size_t ws_size,
                              hipStream_t stream) {
    const float* x = (const float*)d_in[0];   // [4,4096,4096]
    const float* W = (const float*)d_in[1];   // [64,4096]

    float* out    = (float*)d_out;
    float* probs  = out;                         // 16384*64 floats
    float* idxout = out + (size_t)TOKENS * NEXP; // 16384*8 floats (indices as float)

    float* Wt   = (float*)d_ws;                  // 4096*64 floats = 1 MB
    float* part = Wt + (size_t)EMBD * NEXP;      // 8*16384*64 floats = 32 MB

    hipLaunchKernelGGL(transpose_w, dim3((EMBD * NEXP) / 256), dim3(256), 0, stream,
                       W, Wt);
    hipLaunchKernelGGL(gemm_partial, dim3(TOKENS / 128, KSPLIT), dim3(256), 0, stream,
                       x, Wt, part);
    hipLaunchKernelGGL(topk_softmax, dim3(TOKENS / 4), dim3(256), 0, stream,
                       part, probs, idxout);
}